// Round 10
// baseline (60.586 us; speedup 1.0000x reference)
//
#include <hip/hip_runtime.h>
#include <stdint.h>

// IAF inversion via incremental MADE recurrence — barrier-free pipeline.
// 512 single-wave blocks, 2 rows per wave (weights shared by both rows).
// Per-step 6KB packed weights staged into a PRIVATE 8-slot (48KB) LDS
// pipeline via global_load_lds (no register dest -> RA-proof; R2/R4/R5
// lost register prefetch to the allocator). All waits are counted and
// provably pre-satisfied in steady state:
//   s_waitcnt vmcnt(36): needs step u+1 staged -- issued 7 steps earlier.
//   s_waitcnt lgkmcnt(6): needs step u's ds_reads -- issued 1 step earlier
//     (the 6 just-issued reads for u+1 stay in flight).
// LDS->reg one step ahead via volatile asm ds_read_b128 (immovable).
// No s_barrier anywhere (single wave owns the LDS). DPP wave reduction;
// exp(-s)=2^(s') with -1/ln2 folded into packed sigma weights/biases.

#define Bz  1024
#define Dd  128
#define Hh  512
#define LN2 0.6931471805599453f
#define NRL -1.4426950408889634f   // -1/ln2

typedef float v4f __attribute__((ext_vector_type(4)));
typedef const __attribute__((address_space(1))) uint32_t* gas_t;
typedef __attribute__((address_space(3))) uint32_t* las_t;

// ---------------- DPP wave-64 sum ----------------
template<int CTRL, int RMASK>
__device__ __forceinline__ float dpp_add(float v) {
    int t = __builtin_amdgcn_update_dpp(0, __float_as_int(v), CTRL, RMASK, 0xf, true);
    return v + __int_as_float(t);
}
__device__ __forceinline__ float wave_sum_bcast(float v) {
    v = dpp_add<0x111, 0xf>(v);  // row_shr:1
    v = dpp_add<0x112, 0xf>(v);  // row_shr:2
    v = dpp_add<0x114, 0xf>(v);  // row_shr:4
    v = dpp_add<0x118, 0xf>(v);  // row_shr:8
    v = dpp_add<0x142, 0xa>(v);  // row_bcast:15
    v = dpp_add<0x143, 0xc>(v);  // row_bcast:31 -> lane63 = total
    return __int_as_float(__builtin_amdgcn_readlane(__float_as_int(v), 63));
}
__device__ __forceinline__ float bcast_lane(float v, int l) {
    return __int_as_float(__builtin_amdgcn_readlane(__float_as_int(v), l));
}

// ---------------- pre-pack masked weights (verified layout, R7/R8) --------
// Per step d (1536 floats): seg0=[W2sig*mask*(-1/ln2)], seg1=[W2mu*mask],
// seg2=[W1col*mask]. 16B granule g stored at G = g ^ ((g>>3)&7).
__global__ void pack_kernel(const float* __restrict__ W1,
                            const float* __restrict__ W2,
                            float* __restrict__ Wp) {
    int idx = blockIdx.x * blockDim.x + threadIdx.x;
    if (idx >= Dd * 1536) return;
    int d = idx / 1536, f = idx % 1536;
    int seg = f >> 9, h = f & 511;
    int mh = (h % 127) + 1;
    float v;
    if (seg == 0)      v = W2[d * Hh + h]        * ((mh <= d) ? NRL : 0.f);
    else if (seg == 1) v = W2[(Dd + d) * Hh + h] * ((mh <= d) ? 1.f : 0.f);
    else               v = W1[h * Dd + d]        * ((mh >  d) ? 1.f : 0.f);
    int g = (f >> 2) & 127, e = f & 3;
    int G = g ^ ((g >> 3) & 7);
    Wp[d * 1536 + (seg << 9) + G * 4 + e] = v;
}

// ---------------- stage 6KB (one step) global -> LDS slot ----------------
__device__ __forceinline__ void stage6(const float* g, float* l) {
#pragma unroll
    for (int i = 0; i < 6; ++i)
        __builtin_amdgcn_global_load_lds((gas_t)(g + i * 256),
                                         (las_t)(l + i * 256), 16, 0, 0);
}

struct WB { v4f s0, s1, m0, m1, w0, w1; };

// ---------------- one step, two rows (weights in registers) --------------
__device__ __forceinline__ void computeStep2(int u, int lane, const WB& w,
    float (&a0)[8], float (&a1)[8],
    float xa0, float xb0, float xa1, float xb1,
    float b2a, float b2b, float b2c, float b2d_,
    float &za0, float &zb0, float &za1, float &zb1,
    float &ld0, float &ld1)
{
    float A0 = 0.f, A1 = 0.f, B0 = 0.f, B1 = 0.f;   // row0 sig', mu
    float C0 = 0.f, C1 = 0.f, D0 = 0.f, D1 = 0.f;   // row1 sig', mu
#pragma unroll
    for (int k = 0; k < 4; ++k) {
        float h0 = fmaxf(a0[k], 0.f);
        float h1 = fmaxf(a1[k], 0.f);
        A0 = fmaf(h0, w.s0[k], A0);  B0 = fmaf(h0, w.m0[k], B0);
        C0 = fmaf(h1, w.s0[k], C0);  D0 = fmaf(h1, w.m0[k], D0);
    }
#pragma unroll
    for (int k = 0; k < 4; ++k) {
        float h0 = fmaxf(a0[4 + k], 0.f);
        float h1 = fmaxf(a1[4 + k], 0.f);
        A1 = fmaf(h0, w.s1[k], A1);  B1 = fmaf(h0, w.m1[k], B1);
        C1 = fmaf(h1, w.s1[k], C1);  D1 = fmaf(h1, w.m1[k], D1);
    }
    float sp0 = wave_sum_bcast(A0 + A1);
    float sm0 = wave_sum_bcast(B0 + B1);
    float sp1 = wave_sum_bcast(C0 + C1);
    float sm1 = wave_sum_bcast(D0 + D1);

    int dl = u & 63;
    float bs  = bcast_lane(u < 64 ? b2a : b2b, dl);
    float bm  = bcast_lane(u < 64 ? b2c : b2d_, dl);
    float xv0 = bcast_lane(u < 64 ? xa0 : xb0, dl);
    float xv1 = bcast_lane(u < 64 ? xa1 : xb1, dl);

    float s0 = sp0 + bs, s1 = sp1 + bs;     // s' = -s/ln2
    float zd0 = (xv0 - (sm0 + bm)) * __builtin_amdgcn_exp2f(s0);
    float zd1 = (xv1 - (sm1 + bm)) * __builtin_amdgcn_exp2f(s1);
    ld0 += s0;
    ld1 += s1;
    if (dl == lane) {
        if (u < 64) { za0 = zd0; za1 = zd1; }
        else        { zb0 = zd0; zb1 = zd1; }
    }
#pragma unroll
    for (int k = 0; k < 4; ++k) {
        a0[k] = fmaf(zd0, w.w0[k], a0[k]);
        a1[k] = fmaf(zd1, w.w0[k], a1[k]);
    }
#pragma unroll
    for (int k = 0; k < 4; ++k) {
        a0[4 + k] = fmaf(zd0, w.w1[k], a0[4 + k]);
        a1[4 + k] = fmaf(zd1, w.w1[k], a1[4 + k]);
    }
}

__global__ __launch_bounds__(64, 1) void iaf9_kernel(
    const float* __restrict__ x,
    const float* __restrict__ b1,
    const float* __restrict__ b2,
    const float* __restrict__ Wp,
    float* __restrict__ out)
{
    __shared__ float ldsb[8 * 1536];           // 48 KB: 8 private slots
    const int lane = (int)threadIdx.x;
    const int r0   = (int)blockIdx.x * 2;
    const int r1   = r0 + 1;
    const int h0   = lane * 8;

    // ---- per-row state ----
    float a0[8], a1[8];
    {
        float4 t0 = *(const float4*)(b1 + h0);
        float4 t1 = *(const float4*)(b1 + h0 + 4);
        a0[0]=t0.x; a0[1]=t0.y; a0[2]=t0.z; a0[3]=t0.w;
        a0[4]=t1.x; a0[5]=t1.y; a0[6]=t1.z; a0[7]=t1.w;
#pragma unroll
        for (int k = 0; k < 8; ++k) a1[k] = a0[k];
    }
    float xa0 = x[r0 * Dd + lane], xb0 = x[r0 * Dd + 64 + lane];
    float xa1 = x[r1 * Dd + lane], xb1 = x[r1 * Dd + 64 + lane];
    float b2a = b2[lane] * NRL,  b2b = b2[64 + lane] * NRL;
    float b2c = b2[128 + lane],  b2d_ = b2[192 + lane];
    // Pin state + drain ALL prologue vmem before staging (keeps loop counts exact)
    asm volatile("" : "+v"(xa0), "+v"(xb0), "+v"(xa1), "+v"(xb1),
                      "+v"(b2a), "+v"(b2b), "+v"(b2c), "+v"(b2d_));
    asm volatile("" : "+v"(a0[0]), "+v"(a0[1]), "+v"(a0[2]), "+v"(a0[3]),
                      "+v"(a0[4]), "+v"(a0[5]), "+v"(a0[6]), "+v"(a0[7]));
    asm volatile("s_waitcnt vmcnt(0) lgkmcnt(0)" ::: "memory");
    __builtin_amdgcn_sched_barrier(0);

    // ---- prologue: fill all 8 slots (48 loads outstanding) ----
#pragma unroll
    for (int t = 0; t < 8; ++t)
        stage6(Wp + (size_t)t * 1536 + lane * 4, ldsb + t * 1536);

    // swizzled reader LDS byte offsets (lane constants)
    const int g0 = 2 * lane, g1 = 2 * lane + 1;
    const int G0 = g0 ^ ((g0 >> 3) & 7);
    const int G1 = g1 ^ ((g1 >> 3) & 7);
    const unsigned lb0 = (unsigned)(uintptr_t)(las_t)(ldsb) + (unsigned)G0 * 16u;
    const unsigned lb1 = (unsigned)(uintptr_t)(las_t)(ldsb) + (unsigned)G1 * 16u;

#define PREF(SLOT, BUF) do {                                              \
        unsigned _a0 = lb0 + (unsigned)(SLOT) * 6144u;                    \
        unsigned _a1 = lb1 + (unsigned)(SLOT) * 6144u;                    \
        asm volatile("ds_read_b128 %0, %6 offset:0\n\t"                   \
                     "ds_read_b128 %1, %7 offset:0\n\t"                   \
                     "ds_read_b128 %2, %6 offset:2048\n\t"                \
                     "ds_read_b128 %3, %7 offset:2048\n\t"                \
                     "ds_read_b128 %4, %6 offset:4096\n\t"                \
                     "ds_read_b128 %5, %7 offset:4096"                    \
                     : "=v"(BUF.s0), "=v"(BUF.s1), "=v"(BUF.m0),          \
                       "=v"(BUF.m1), "=v"(BUF.w0), "=v"(BUF.w1)           \
                     : "v"(_a0), "v"(_a1));                               \
    } while (0)

    asm volatile("s_waitcnt vmcnt(36)" ::: "memory");  // steps 0,1 staged
    __builtin_amdgcn_sched_barrier(0);

    WB P, Q;
    PREF(0, P);

    float za0 = 0.f, zb0 = 0.f, za1 = 0.f, zb1 = 0.f;
    float ld0 = 0.f, ld1 = 0.f;
    const float* gp = Wp + (size_t)8 * 1536 + lane * 4;  // next step to stage

    // Per sub-step u = t0+C:
    //   vmcnt(36): step u+1 staged (issued 7 steps ago -> pre-satisfied)
    //   PREF(u+1 -> NXT)   (volatile asm, immovable, latency hidden 1 step)
    //   lgkmcnt(6): CUR's reads done (issued 1 step ago); NXT's 6 in flight
    //   stage6(u+8 -> slot u&7)  (slot's reads retired by lgkmcnt(6))
    //   computeStep2(u) from CUR
#define SUB(C, CUR, NXT, STG) do {                                        \
        const int u = t0 + (C);                                           \
        asm volatile("s_waitcnt vmcnt(36)" ::: "memory");                 \
        __builtin_amdgcn_sched_barrier(0);                                \
        PREF(((C) + 1) & 7, NXT);                                         \
        asm volatile("s_waitcnt lgkmcnt(6)" ::: "memory");                \
        __builtin_amdgcn_sched_barrier(0);                                \
        if (STG) { stage6(gp, ldsb + (C) * 1536); }                       \
        gp += 1536;                                                       \
        computeStep2(u, lane, CUR, a0, a1, xa0, xb0, xa1, xb1,            \
                     b2a, b2b, b2c, b2d_, za0, zb0, za1, zb1, ld0, ld1);  \
    } while (0)

#pragma unroll 1
    for (int t0 = 0; t0 < Dd - 8; t0 += 8) {   // t0 = 0..112: always stage
        SUB(0, P, Q, 1);
        SUB(1, Q, P, 1);
        SUB(2, P, Q, 1);
        SUB(3, Q, P, 1);
        SUB(4, P, Q, 1);
        SUB(5, Q, P, 1);
        SUB(6, P, Q, 1);
        SUB(7, Q, P, 1);
    }
    {   // tail t0 = 120: no staging (slots already hold steps 120..127)
        const int t0 = Dd - 8;
        SUB(0, P, Q, 0);
        SUB(1, Q, P, 0);
        SUB(2, P, Q, 0);
        SUB(3, Q, P, 0);
        SUB(4, P, Q, 0);
        SUB(5, Q, P, 0);
        SUB(6, P, Q, 0);
        SUB(7, Q, P, 0);
    }
#undef SUB
#undef PREF

    out[r0 * Dd + lane]      = za0;
    out[r0 * Dd + 64 + lane] = zb0;
    out[r1 * Dd + lane]      = za1;
    out[r1 * Dd + 64 + lane] = zb1;
    if (lane == 0) {
        out[Bz * Dd + r0] = LN2 * ld0;
        out[Bz * Dd + r1] = LN2 * ld1;
    }
}

// ---------------- fallback (ws too small): masked direct loads ----------------
__global__ __launch_bounds__(64, 1) void iaf_fb_kernel(
    const float* __restrict__ x,  const float* __restrict__ W1,
    const float* __restrict__ b1, const float* __restrict__ W2,
    const float* __restrict__ b2, float* __restrict__ out)
{
    const int lane = (int)threadIdx.x;
    const int row  = (int)blockIdx.x;
    const int h0   = lane * 8;
    float a[8]; int mh[8];
#pragma unroll
    for (int k = 0; k < 8; ++k) { a[k] = b1[h0 + k]; mh[k] = ((h0 + k) % 127) + 1; }
    float xa  = x[row * Dd + lane], xb = x[row * Dd + 64 + lane];
    float b2a = b2[lane], b2b = b2[64 + lane], b2c = b2[128 + lane], b2d_ = b2[192 + lane];
    float za = 0.f, zb = 0.f, ld = 0.f;
    for (int d = 0; d < Dd; ++d) {
        float ps = 0.f, pm = 0.f;
#pragma unroll
        for (int k = 0; k < 8; ++k) {
            float h = fmaxf(a[k], 0.f);
            h = (mh[k] <= d) ? h : 0.f;
            ps = fmaf(h, W2[d * Hh + h0 + k], ps);
            pm = fmaf(h, W2[(Dd + d) * Hh + h0 + k], pm);
        }
        ps = wave_sum_bcast(ps);
        pm = wave_sum_bcast(pm);
        int dl = d & 63;
        float sd = ps + bcast_lane(d < 64 ? b2a : b2b, dl);
        float md = pm + bcast_lane(d < 64 ? b2c : b2d_, dl);
        float xv =      bcast_lane(d < 64 ? xa  : xb,  dl);
        float zd = (xv - md) * __expf(-sd);
        ld -= sd;
        if (dl == lane) { if (d < 64) za = zd; else zb = zd; }
#pragma unroll
        for (int k = 0; k < 8; ++k)
            if (d < mh[k]) a[k] = fmaf(zd, W1[(h0 + k) * Dd + d], a[k]);
    }
    out[row * Dd + lane]      = za;
    out[row * Dd + 64 + lane] = zb;
    if (lane == 0) out[Bz * Dd + row] = ld;
}

extern "C" void kernel_launch(void* const* d_in, const int* in_sizes, int n_in,
                              void* d_out, int out_size, void* d_ws, size_t ws_size,
                              hipStream_t stream) {
    const float* x  = (const float*)d_in[0];
    const float* W1 = (const float*)d_in[1];
    const float* b1 = (const float*)d_in[2];
    const float* W2 = (const float*)d_in[3];
    const float* b2 = (const float*)d_in[4];
    float* out = (float*)d_out;
    float* Wp  = (float*)d_ws;

    const size_t need = (size_t)Dd * 1536 * sizeof(float);  // 768 KB
    if (ws_size >= need) {
        pack_kernel<<<(Dd * 1536 + 255) / 256, 256, 0, stream>>>(W1, W2, Wp);
        iaf9_kernel<<<Bz / 2, 64, 0, stream>>>(x, b1, b2, Wp, out);
    } else {
        iaf_fb_kernel<<<Bz, 64, 0, stream>>>(x, W1, b1, W2, b2, out);
    }
}

// Round 11
// 42.794 us; speedup vs baseline: 1.4158x; 1.4158x over previous
//
#include <hip/hip_runtime.h>
#include <stdint.h>

// IAF inversion via incremental MADE recurrence — span-pipelined CU sharing.
// 256 blocks x 4 waves (1 block/CU), 1 row/wave. Per-step 6KB packed weights
// are read by all 4 waves from a shared 16-slot (96KB) LDS ring:
//   span = 8 steps. ONE raw s_barrier per span. After the barrier each wave
//   issues its 12 global_load_lds for the NEXT span (slots vacated a span
//   ago), then computes 8 steps from the current span's slots.
//   Span-end s_waitcnt vmcnt(0) drains loads issued ~8 steps (~1500+cyc)
//   earlier -> pre-satisfied; barrier cost amortized /8.
// This cuts per-CU weight traffic 4x vs all prior rounds (R4-R9 all paid
// ~6KB/step/WAVE through VMEM -> 400-750cyc/step floor at 4 waves/CU).
// LDS->reg one step ahead via volatile asm ds_read_b128 + lgkmcnt(6).
// DPP wave reduction; exp(-s)=2^(s') with -1/ln2 folded into weights.

#define Bz  1024
#define Dd  128
#define Hh  512
#define LN2 0.6931471805599453f
#define NRL -1.4426950408889634f   // -1/ln2

typedef float v4f __attribute__((ext_vector_type(4)));
typedef const __attribute__((address_space(1))) uint32_t* gas_t;
typedef __attribute__((address_space(3))) uint32_t* las_t;

// ---------------- DPP wave-64 sum ----------------
template<int CTRL, int RMASK>
__device__ __forceinline__ float dpp_add(float v) {
    int t = __builtin_amdgcn_update_dpp(0, __float_as_int(v), CTRL, RMASK, 0xf, true);
    return v + __int_as_float(t);
}
__device__ __forceinline__ float wave_sum_bcast(float v) {
    v = dpp_add<0x111, 0xf>(v);  // row_shr:1
    v = dpp_add<0x112, 0xf>(v);  // row_shr:2
    v = dpp_add<0x114, 0xf>(v);  // row_shr:4
    v = dpp_add<0x118, 0xf>(v);  // row_shr:8
    v = dpp_add<0x142, 0xa>(v);  // row_bcast:15
    v = dpp_add<0x143, 0xc>(v);  // row_bcast:31 -> lane63 = total
    return __int_as_float(__builtin_amdgcn_readlane(__float_as_int(v), 63));
}
__device__ __forceinline__ float bcast_lane(float v, int l) {
    return __int_as_float(__builtin_amdgcn_readlane(__float_as_int(v), l));
}

// ---------------- pre-pack masked weights (verified layout R7-R9) ---------
// Per step d (1536 floats): seg0=[W2sig*mask*(-1/ln2)], seg1=[W2mu*mask],
// seg2=[W1col*mask]. 16B granule g stored at G = g ^ ((g>>3)&7).
__global__ void pack_kernel(const float* __restrict__ W1,
                            const float* __restrict__ W2,
                            float* __restrict__ Wp) {
    int idx = blockIdx.x * blockDim.x + threadIdx.x;
    if (idx >= Dd * 1536) return;
    int d = idx / 1536, f = idx % 1536;
    int seg = f >> 9, h = f & 511;
    int mh = (h % 127) + 1;
    float v;
    if (seg == 0)      v = W2[d * Hh + h]        * ((mh <= d) ? NRL : 0.f);
    else if (seg == 1) v = W2[(Dd + d) * Hh + h] * ((mh <= d) ? 1.f : 0.f);
    else               v = W1[h * Dd + d]        * ((mh >  d) ? 1.f : 0.f);
    int g = (f >> 2) & 127, e = f & 3;
    int G = g ^ ((g >> 3) & 7);
    Wp[d * 1536 + (seg << 9) + G * 4 + e] = v;
}

// ---------------- stage 6KB (one step) global -> LDS slot ----------------
__device__ __forceinline__ void stage6(const float* g, float* l) {
#pragma unroll
    for (int i = 0; i < 6; ++i)
        __builtin_amdgcn_global_load_lds((gas_t)(g + i * 256),
                                         (las_t)(l + i * 256), 16, 0, 0);
}

struct WB { v4f s0, s1, m0, m1, w0, w1; };

// ---------------- one recurrence step (weights in registers) -------------
__device__ __forceinline__ void computeStep(int u, int lane, const WB& w,
    float (&a)[8], float xa, float xb,
    float b2a, float b2b, float b2c, float b2d_,
    float &za, float &zb, float &ldet)
{
    float ps0 = 0.f, ps1 = 0.f, pm0 = 0.f, pm1 = 0.f;
#pragma unroll
    for (int k = 0; k < 4; ++k) {
        float hv = fmaxf(a[k], 0.f);
        ps0 = fmaf(hv, w.s0[k], ps0);
        pm0 = fmaf(hv, w.m0[k], pm0);
    }
#pragma unroll
    for (int k = 0; k < 4; ++k) {
        float hv = fmaxf(a[4 + k], 0.f);
        ps1 = fmaf(hv, w.s1[k], ps1);
        pm1 = fmaf(hv, w.m1[k], pm1);
    }
    float sp = wave_sum_bcast(ps0 + ps1);   // s' partial (= -s/ln2 part)
    float sm = wave_sum_bcast(pm0 + pm1);   // mu partial

    int dl = u & 63;
    float bs = bcast_lane(u < 64 ? b2a : b2b, dl);
    float bm = bcast_lane(u < 64 ? b2c : b2d_, dl);
    float xv = bcast_lane(u < 64 ? xa  : xb,  dl);

    float sd = sp + bs;                       // s' = -s/ln2
    float zd = (xv - (sm + bm)) * __builtin_amdgcn_exp2f(sd);
    ldet += sd;
    if (dl == lane) { if (u < 64) za = zd; else zb = zd; }

#pragma unroll
    for (int k = 0; k < 4; ++k) a[k]     = fmaf(zd, w.w0[k], a[k]);
#pragma unroll
    for (int k = 0; k < 4; ++k) a[4 + k] = fmaf(zd, w.w1[k], a[4 + k]);
}

__global__ __launch_bounds__(256, 1) void iaf10_kernel(
    const float* __restrict__ x,
    const float* __restrict__ b1,
    const float* __restrict__ b2,
    const float* __restrict__ Wp,
    float* __restrict__ out)
{
    __shared__ float ldsb[16 * 1536];          // 96 KB: 16-slot ring (2 spans)
    const int tid  = (int)threadIdx.x;
    const int lane = tid & 63;
    const int wid  = tid >> 6;                 // wave 0..3
    const int row  = (int)blockIdx.x * 4 + wid;
    const int h0   = lane * 8;

    // ---- per-row state ----
    float a[8];
    {
        float4 t0v = *(const float4*)(b1 + h0);
        float4 t1v = *(const float4*)(b1 + h0 + 4);
        a[0]=t0v.x; a[1]=t0v.y; a[2]=t0v.z; a[3]=t0v.w;
        a[4]=t1v.x; a[5]=t1v.y; a[6]=t1v.z; a[7]=t1v.w;
    }
    float xa  = x[row * Dd + lane];
    float xb  = x[row * Dd + 64 + lane];
    float b2a = b2[lane] * NRL,  b2b = b2[64 + lane] * NRL;
    float b2c = b2[128 + lane],  b2d_ = b2[192 + lane];
    // pin state + drain all compiler-visible vmem before manual counting
    asm volatile("" : "+v"(xa), "+v"(xb), "+v"(b2a), "+v"(b2b), "+v"(b2c),
                      "+v"(b2d_), "+v"(a[0]), "+v"(a[1]), "+v"(a[2]),
                      "+v"(a[3]), "+v"(a[4]), "+v"(a[5]), "+v"(a[6]), "+v"(a[7]));
    asm volatile("s_waitcnt vmcnt(0) lgkmcnt(0)" ::: "memory");
    __builtin_amdgcn_sched_barrier(0);

    // ---- prologue: stage span 0 (wave w stages steps 2w, 2w+1) ----
    stage6(Wp + (size_t)(2 * wid) * 1536 + lane * 4,     ldsb + (2 * wid) * 1536);
    stage6(Wp + (size_t)(2 * wid + 1) * 1536 + lane * 4, ldsb + (2 * wid + 1) * 1536);
    asm volatile("s_waitcnt vmcnt(0)" ::: "memory");
    __builtin_amdgcn_sched_barrier(0);
    __builtin_amdgcn_s_barrier();
    __builtin_amdgcn_sched_barrier(0);

    // swizzled reader LDS byte offsets (lane constants)
    const int g0 = 2 * lane, g1 = 2 * lane + 1;
    const int G0 = g0 ^ ((g0 >> 3) & 7);
    const int G1 = g1 ^ ((g1 >> 3) & 7);
    const unsigned lb0 = (unsigned)(uintptr_t)(las_t)(ldsb) + (unsigned)G0 * 16u;
    const unsigned lb1 = (unsigned)(uintptr_t)(las_t)(ldsb) + (unsigned)G1 * 16u;

#define PREF(SLOT, BUF) do {                                              \
        unsigned _a0 = lb0 + (unsigned)(SLOT) * 6144u;                    \
        unsigned _a1 = lb1 + (unsigned)(SLOT) * 6144u;                    \
        asm volatile("ds_read_b128 %0, %6 offset:0\n\t"                   \
                     "ds_read_b128 %1, %7 offset:0\n\t"                   \
                     "ds_read_b128 %2, %6 offset:2048\n\t"                \
                     "ds_read_b128 %3, %7 offset:2048\n\t"                \
                     "ds_read_b128 %4, %6 offset:4096\n\t"                \
                     "ds_read_b128 %5, %7 offset:4096"                    \
                     : "=v"(BUF.s0), "=v"(BUF.s1), "=v"(BUF.m0),          \
                       "=v"(BUF.m1), "=v"(BUF.w0), "=v"(BUF.w1)           \
                     : "v"(_a0), "v"(_a1));                               \
    } while (0)

    WB P, Q;
    float za = 0.f, zb = 0.f, ldet = 0.f;

    // Per sub-step C (u = t0+C), CUR prefetched one step earlier:
    //   C<7: PREF(C+1 -> NXT); lgkmcnt(6)   (CUR ready; NXT in flight)
    //   C=7: lgkmcnt(0)                     (CUR issued at C=6 -> ~free)
#define SUBX(C, CUR, NXT) do {                                            \
        if ((C) < 7) {                                                    \
            PREF(H8 + (C) + 1, NXT);                                      \
            asm volatile("s_waitcnt lgkmcnt(6)" ::: "memory");            \
        } else {                                                          \
            asm volatile("s_waitcnt lgkmcnt(0)" ::: "memory");            \
        }                                                                 \
        __builtin_amdgcn_sched_barrier(0);                                \
        computeStep(t0 + (C), lane, CUR, a, xa, xb, b2a, b2b, b2c, b2d_,  \
                    za, zb, ldet);                                        \
    } while (0)

#pragma unroll 1
    for (int t0 = 0; t0 < Dd; t0 += 8) {       // 16 spans of 8 steps
        const int H8 = t0 & 8;                 // current ring half (0 or 8)

        PREF(H8, P);                           // first step of span -> P

        if (t0 + 8 < Dd) {                     // stage next span (12 loads)
            const int s0 = t0 + 8 + 2 * wid;
            stage6(Wp + (size_t)s0 * 1536 + lane * 4,
                   ldsb + (s0 & 15) * 1536);
            stage6(Wp + (size_t)(s0 + 1) * 1536 + lane * 4,
                   ldsb + ((s0 + 1) & 15) * 1536);
        }
        __builtin_amdgcn_sched_barrier(0);

        SUBX(0, P, Q);
        SUBX(1, Q, P);
        SUBX(2, P, Q);
        SUBX(3, Q, P);
        SUBX(4, P, Q);
        SUBX(5, Q, P);
        SUBX(6, P, Q);
        SUBX(7, Q, P);

        // span end: drain own stages (issued ~8 steps ago), publish slots
        asm volatile("s_waitcnt vmcnt(0)" ::: "memory");
        __builtin_amdgcn_sched_barrier(0);
        __builtin_amdgcn_s_barrier();
        __builtin_amdgcn_sched_barrier(0);
    }
#undef SUBX
#undef PREF

    asm volatile("s_waitcnt vmcnt(0) lgkmcnt(0)" ::: "memory");
    out[row * Dd + lane]      = za;
    out[row * Dd + 64 + lane] = zb;
    if (lane == 0) out[Bz * Dd + row] = LN2 * ldet;
}

// ---------------- fallback (ws too small): masked direct loads ----------------
__global__ __launch_bounds__(64, 1) void iaf_fb_kernel(
    const float* __restrict__ x,  const float* __restrict__ W1,
    const float* __restrict__ b1, const float* __restrict__ W2,
    const float* __restrict__ b2, float* __restrict__ out)
{
    const int lane = (int)threadIdx.x;
    const int row  = (int)blockIdx.x;
    const int h0   = lane * 8;
    float a[8]; int mh[8];
#pragma unroll
    for (int k = 0; k < 8; ++k) { a[k] = b1[h0 + k]; mh[k] = ((h0 + k) % 127) + 1; }
    float xa  = x[row * Dd + lane], xb = x[row * Dd + 64 + lane];
    float b2a = b2[lane], b2b = b2[64 + lane], b2c = b2[128 + lane], b2d_ = b2[192 + lane];
    float za = 0.f, zb = 0.f, ld = 0.f;
    for (int d = 0; d < Dd; ++d) {
        float ps = 0.f, pm = 0.f;
#pragma unroll
        for (int k = 0; k < 8; ++k) {
            float h = fmaxf(a[k], 0.f);
            h = (mh[k] <= d) ? h : 0.f;
            ps = fmaf(h, W2[d * Hh + h0 + k], ps);
            pm = fmaf(h, W2[(Dd + d) * Hh + h0 + k], pm);
        }
        ps = wave_sum_bcast(ps);
        pm = wave_sum_bcast(pm);
        int dl = d & 63;
        float sd = ps + bcast_lane(d < 64 ? b2a : b2b, dl);
        float md = pm + bcast_lane(d < 64 ? b2c : b2d_, dl);
        float xv =      bcast_lane(d < 64 ? xa  : xb,  dl);
        float zd = (xv - md) * __expf(-sd);
        ld -= sd;
        if (dl == lane) { if (d < 64) za = zd; else zb = zd; }
#pragma unroll
        for (int k = 0; k < 8; ++k)
            if (d < mh[k]) a[k] = fmaf(zd, W1[(h0 + k) * Dd + d], a[k]);
    }
    out[row * Dd + lane]      = za;
    out[row * Dd + 64 + lane] = zb;
    if (lane == 0) out[Bz * Dd + row] = ld;
}

extern "C" void kernel_launch(void* const* d_in, const int* in_sizes, int n_in,
                              void* d_out, int out_size, void* d_ws, size_t ws_size,
                              hipStream_t stream) {
    const float* x  = (const float*)d_in[0];
    const float* W1 = (const float*)d_in[1];
    const float* b1 = (const float*)d_in[2];
    const float* W2 = (const float*)d_in[3];
    const float* b2 = (const float*)d_in[4];
    float* out = (float*)d_out;
    float* Wp  = (float*)d_ws;

    const size_t need = (size_t)Dd * 1536 * sizeof(float);  // 768 KB
    if (ws_size >= need) {
        pack_kernel<<<(Dd * 1536 + 255) / 256, 256, 0, stream>>>(W1, W2, Wp);
        iaf10_kernel<<<Bz / 4, 256, 0, stream>>>(x, b1, b2, Wp, out);
    } else {
        iaf_fb_kernel<<<Bz, 64, 0, stream>>>(x, W1, b1, W2, b2, out);
    }
}

// Round 13
// 33.121 us; speedup vs baseline: 1.8293x; 1.2921x over previous
//
#include <hip/hip_runtime.h>
#include <stdint.h>

// IAF inversion via incremental MADE recurrence — R4 skeleton (best: 38.7us,
// plain C++ quad-buffered register prefetch, no LDS, no barriers, no asm
// loads) + instruction-count reduction:
//   * v_pk_fma_f32/v_pk_max_f32 packed pairs (dot 16->8, relu 8->4, upd 8->4)
//   * all bias work folded out of the loop (exact; b2==0 here anyway):
//       x' = x - b2_mu (prologue); sigma bias -> epilogue *E_d + Csum;
//       W1col pre-scaled by E_d in pack; loop has ZERO bias instructions.
// 1024 single-wave blocks (1 wave/SIMD). DPP wave reduction.
// exp(-s) = 2^(s') with -1/ln2 folded into packed sigma weights.

#define Bz  1024
#define Dd  128
#define Hh  512
#define LN2 0.6931471805599453f
#define NRL -1.4426950408889634f   // -1/ln2

typedef float v4f __attribute__((ext_vector_type(4)));
typedef float v2f __attribute__((ext_vector_type(2)));

#define LOQ(q) __builtin_shufflevector(q, q, 0, 1)
#define HIQ(q) __builtin_shufflevector(q, q, 2, 3)

// ---------------- DPP wave-64 sum ----------------
template<int CTRL, int RMASK>
__device__ __forceinline__ float dpp_add(float v) {
    int t = __builtin_amdgcn_update_dpp(0, __float_as_int(v), CTRL, RMASK, 0xf, true);
    return v + __int_as_float(t);
}
__device__ __forceinline__ float wave_sum_bcast(float v) {
    v = dpp_add<0x111, 0xf>(v);  // row_shr:1
    v = dpp_add<0x112, 0xf>(v);  // row_shr:2
    v = dpp_add<0x114, 0xf>(v);  // row_shr:4
    v = dpp_add<0x118, 0xf>(v);  // row_shr:8
    v = dpp_add<0x142, 0xa>(v);  // row_bcast:15
    v = dpp_add<0x143, 0xc>(v);  // row_bcast:31 -> lane63 = total
    return __int_as_float(__builtin_amdgcn_readlane(__float_as_int(v), 63));
}
__device__ __forceinline__ float bcast_lane(float v, int l) {
    return __int_as_float(__builtin_amdgcn_readlane(__float_as_int(v), l));
}

// ---------------- pre-pack masked weights (R4 plain layout + folds) -------
// Wp[d*1536 + 0..511]     = W2[d,h]   * (m_hid<=d) * (-1/ln2)    (sigma')
// Wp[d*1536 + 512..1023]  = W2[D+d,h] * (m_hid<=d)               (mu)
// Wp[d*1536 + 1024..1535] = W1[h,d]   * (m_hid> d) * exp(-b2[d]) (E_d fold)
__global__ void pack_kernel(const float* __restrict__ W1,
                            const float* __restrict__ W2,
                            const float* __restrict__ b2,
                            float* __restrict__ Wp) {
    int idx = blockIdx.x * blockDim.x + threadIdx.x;
    if (idx >= Dd * Hh) return;
    int d = idx >> 9, h = idx & 511;
    int mh = (h % 127) + 1;
    float* bp = Wp + d * 1536;
    bp[h]        = W2[d * Hh + h] * ((mh <= d) ? NRL : 0.f);
    bp[512 + h]  = W2[(Dd + d) * Hh + h] * ((mh <= d) ? 1.f : 0.f);
    bp[1024 + h] = W1[h * Dd + d] * ((mh > d) ? __expf(-b2[d]) : 0.f);
}

// ---------------- weight buffer (24 VGPRs each) ----------------
struct WBuf { v4f s0, s1, m0, m1, w0, w1; };

__device__ __forceinline__ void loadbuf(WBuf &b, const float* p) {
    b.s0 = *(const v4f*)(p);          // sigma' (masked, *NRL)
    b.s1 = *(const v4f*)(p + 4);
    b.m0 = *(const v4f*)(p + 512);    // mu (masked)
    b.m1 = *(const v4f*)(p + 516);
    b.w0 = *(const v4f*)(p + 1024);   // W1 col (masked, *E_d)
    b.w1 = *(const v4f*)(p + 1028);
    __builtin_amdgcn_sched_barrier(0);  // pin issue point
}

// ---------------- one recurrence step (pk math, zero bias work) ----------
__device__ __forceinline__ void stepD(int u, int lane,
    v2f (&a2)[4], const WBuf &w, float xa, float xb,
    float &za, float &zb, float &ldet)
{
    const v2f zz = {0.f, 0.f};
    v2f h0 = __builtin_elementwise_max(a2[0], zz);
    v2f h1 = __builtin_elementwise_max(a2[1], zz);
    v2f h2 = __builtin_elementwise_max(a2[2], zz);
    v2f h3 = __builtin_elementwise_max(a2[3], zz);

    v2f psA = zz, psB = zz, pmA = zz, pmB = zz;
    psA = __builtin_elementwise_fma(h0, (v2f)LOQ(w.s0), psA);
    pmA = __builtin_elementwise_fma(h0, (v2f)LOQ(w.m0), pmA);
    psB = __builtin_elementwise_fma(h1, (v2f)HIQ(w.s0), psB);
    pmB = __builtin_elementwise_fma(h1, (v2f)HIQ(w.m0), pmB);
    psA = __builtin_elementwise_fma(h2, (v2f)LOQ(w.s1), psA);
    pmA = __builtin_elementwise_fma(h2, (v2f)LOQ(w.m1), pmA);
    psB = __builtin_elementwise_fma(h3, (v2f)HIQ(w.s1), psB);
    pmB = __builtin_elementwise_fma(h3, (v2f)HIQ(w.m1), pmB);
    v2f psp = psA + psB;             // v_pk_add_f32
    v2f pmp = pmA + pmB;

    float sp = wave_sum_bcast(psp.x + psp.y);   // s' = -s/ln2 (no bias)
    float sm = wave_sum_bcast(pmp.x + pmp.y);   // mu (bias folded into x)

    int dl = u & 63;
    float xv = bcast_lane(u < 64 ? xa : xb, dl);
    float zd = (xv - sm) * __builtin_amdgcn_exp2f(sp);  // z_true / E_d
    ldet += sp;
    if (dl == lane) { if (u < 64) za = zd; else zb = zd; }

    v2f zd2 = {zd, zd};
    a2[0] = __builtin_elementwise_fma(zd2, (v2f)LOQ(w.w0), a2[0]);
    a2[1] = __builtin_elementwise_fma(zd2, (v2f)HIQ(w.w0), a2[1]);
    a2[2] = __builtin_elementwise_fma(zd2, (v2f)LOQ(w.w1), a2[2]);
    a2[3] = __builtin_elementwise_fma(zd2, (v2f)HIQ(w.w1), a2[3]);
}

__global__ __launch_bounds__(64, 1) void iaf12_kernel(
    const float* __restrict__ x,
    const float* __restrict__ b1,
    const float* __restrict__ b2,
    const float* __restrict__ Wp,
    float* __restrict__ out)
{
    const int lane = (int)threadIdx.x;
    const int row  = (int)blockIdx.x;
    const int h0   = lane * 8;

    // ---- per-row state: preacts (pk pairs), bias-folded x, epilogue E ----
    v2f a2[4];
    {
        v4f t0v = *(const v4f*)(b1 + h0);
        v4f t1v = *(const v4f*)(b1 + h0 + 4);
        a2[0] = LOQ(t0v); a2[1] = HIQ(t0v);
        a2[2] = LOQ(t1v); a2[3] = HIQ(t1v);
    }
    float bsa = b2[lane],       bsb = b2[64 + lane];    // sigma biases
    float bma = b2[128 + lane], bmb = b2[192 + lane];   // mu biases
    float xa  = x[row * Dd + lane]      - bma;          // x' = x - b2_mu
    float xb  = x[row * Dd + 64 + lane] - bmb;
    float Ea  = __builtin_amdgcn_exp2f(bsa * NRL);      // E_d for za lanes
    float Eb  = __builtin_amdgcn_exp2f(bsb * NRL);      // E_d for zb lanes
    float Csum = NRL * wave_sum_bcast(bsa + bsb);       // sum_d b2[d]*NRL

    float za = 0.f, zb = 0.f, ldet = 0.f;

    const float* base = Wp + h0;
    WBuf A, B, C, D;
    loadbuf(A, base + 0 * 1536);
    loadbuf(B, base + 1 * 1536);
    loadbuf(C, base + 2 * 1536);
    loadbuf(D, base + 3 * 1536);

#pragma unroll 1
    for (int t = 0; t < Dd; t += 4) {
        stepD(t + 0, lane, a2, A, xa, xb, za, zb, ldet);
        loadbuf(A, base + (size_t)((t + 4 < Dd) ? (t + 4) : 0) * 1536);
        stepD(t + 1, lane, a2, B, xa, xb, za, zb, ldet);
        loadbuf(B, base + (size_t)((t + 5 < Dd) ? (t + 5) : 1) * 1536);
        stepD(t + 2, lane, a2, C, xa, xb, za, zb, ldet);
        loadbuf(C, base + (size_t)((t + 6 < Dd) ? (t + 6) : 2) * 1536);
        stepD(t + 3, lane, a2, D, xa, xb, za, zb, ldet);
        loadbuf(D, base + (size_t)((t + 7 < Dd) ? (t + 7) : 3) * 1536);
    }

    out[row * Dd + lane]      = za * Ea;       // un-fold E_d
    out[row * Dd + 64 + lane] = zb * Eb;
    if (lane == 0) out[Bz * Dd + row] = LN2 * (ldet + Csum);
}

// ---------------- fallback (ws too small): masked direct loads ----------------
__global__ __launch_bounds__(64, 1) void iaf_fb_kernel(
    const float* __restrict__ x,  const float* __restrict__ W1,
    const float* __restrict__ b1, const float* __restrict__ W2,
    const float* __restrict__ b2, float* __restrict__ out)
{
    const int lane = (int)threadIdx.x;
    const int row  = (int)blockIdx.x;
    const int h0   = lane * 8;
    float a[8]; int mh[8];
#pragma unroll
    for (int k = 0; k < 8; ++k) { a[k] = b1[h0 + k]; mh[k] = ((h0 + k) % 127) + 1; }
    float xa  = x[row * Dd + lane], xb = x[row * Dd + 64 + lane];
    float b2a = b2[lane], b2b = b2[64 + lane], b2c = b2[128 + lane], b2d_ = b2[192 + lane];
    float za = 0.f, zb = 0.f, ld = 0.f;
    for (int d = 0; d < Dd; ++d) {
        float ps = 0.f, pm = 0.f;
#pragma unroll
        for (int k = 0; k < 8; ++k) {
            float h = fmaxf(a[k], 0.f);
            h = (mh[k] <= d) ? h : 0.f;
            ps = fmaf(h, W2[d * Hh + h0 + k], ps);
            pm = fmaf(h, W2[(Dd + d) * Hh + h0 + k], pm);
        }
        ps = wave_sum_bcast(ps);
        pm = wave_sum_bcast(pm);
        int dl = d & 63;
        float sd = ps + bcast_lane(d < 64 ? b2a : b2b, dl);
        float md = pm + bcast_lane(d < 64 ? b2c : b2d_, dl);
        float xv =      bcast_lane(d < 64 ? xa  : xb,  dl);
        float zd = (xv - md) * __expf(-sd);
        ld -= sd;
        if (dl == lane) { if (d < 64) za = zd; else zb = zd; }
#pragma unroll
        for (int k = 0; k < 8; ++k)
            if (d < mh[k]) a[k] = fmaf(zd, W1[(h0 + k) * Dd + d], a[k]);
    }
    out[row * Dd + lane]      = za;
    out[row * Dd + 64 + lane] = zb;
    if (lane == 0) out[Bz * Dd + row] = ld;
}

extern "C" void kernel_launch(void* const* d_in, const int* in_sizes, int n_in,
                              void* d_out, int out_size, void* d_ws, size_t ws_size,
                              hipStream_t stream) {
    const float* x  = (const float*)d_in[0];
    const float* W1 = (const float*)d_in[1];
    const float* b1 = (const float*)d_in[2];
    const float* W2 = (const float*)d_in[3];
    const float* b2 = (const float*)d_in[4];
    float* out = (float*)d_out;
    float* Wp  = (float*)d_ws;

    const size_t need = (size_t)Dd * 1536 * sizeof(float);  // 768 KB
    if (ws_size >= need) {
        pack_kernel<<<(Dd * Hh + 255) / 256, 256, 0, stream>>>(W1, W2, b2, Wp);
        iaf12_kernel<<<Bz, 64, 0, stream>>>(x, b1, b2, Wp, out);
    } else {
        iaf_fb_kernel<<<Bz, 64, 0, stream>>>(x, W1, b1, W2, b2, out);
    }
}

// Round 14
// 33.028 us; speedup vs baseline: 1.8344x; 1.0028x over previous
//
#include <hip/hip_runtime.h>
#include <stdint.h>

// IAF inversion via incremental MADE recurrence — R12 skeleton (33.1us best)
// with: 3-buffer rotation (72 buf VGPRs; fits the ~104-VGPR grant the RA has
// repeatedly given -> prefetched loads provably stay resident, no remat), and
// lane-63 reduction (no sp/sm readlanes; zd computed on lane63, ONE readlane
// broadcast; ldet accumulated on lane63 only).
// 1024 single-wave blocks (1 wave/SIMD), pk-packed f32 math, biases folded
// out of the loop entirely (exact; b2==0 here anyway).

#define Bz  1024
#define Dd  128
#define Hh  512
#define LN2 0.6931471805599453f
#define NRL -1.4426950408889634f   // -1/ln2

typedef float v4f __attribute__((ext_vector_type(4)));
typedef float v2f __attribute__((ext_vector_type(2)));

#define LOQ(q) __builtin_shufflevector(q, q, 0, 1)
#define HIQ(q) __builtin_shufflevector(q, q, 2, 3)

// ---------------- DPP wave-64 sum ----------------
template<int CTRL, int RMASK>
__device__ __forceinline__ float dpp_add(float v) {
    int t = __builtin_amdgcn_update_dpp(0, __float_as_int(v), CTRL, RMASK, 0xf, true);
    return v + __int_as_float(t);
}
__device__ __forceinline__ float wave_sum63(float v) {   // total in lane 63
    v = dpp_add<0x111, 0xf>(v);  // row_shr:1
    v = dpp_add<0x112, 0xf>(v);  // row_shr:2
    v = dpp_add<0x114, 0xf>(v);  // row_shr:4
    v = dpp_add<0x118, 0xf>(v);  // row_shr:8
    v = dpp_add<0x142, 0xa>(v);  // row_bcast:15
    v = dpp_add<0x143, 0xc>(v);  // row_bcast:31
    return v;
}
__device__ __forceinline__ float bcast_lane(float v, int l) {
    return __int_as_float(__builtin_amdgcn_readlane(__float_as_int(v), l));
}
__device__ __forceinline__ float wave_sum_bcast(float v) {
    return bcast_lane(wave_sum63(v), 63);
}

// ---------------- pre-pack masked weights (R12 layout, verified) ----------
// Wp[d*1536 + 0..511]     = W2[d,h]   * (m_hid<=d) * (-1/ln2)    (sigma')
// Wp[d*1536 + 512..1023]  = W2[D+d,h] * (m_hid<=d)               (mu)
// Wp[d*1536 + 1024..1535] = W1[h,d]   * (m_hid> d) * exp(-b2[d]) (E_d fold)
__global__ void pack_kernel(const float* __restrict__ W1,
                            const float* __restrict__ W2,
                            const float* __restrict__ b2,
                            float* __restrict__ Wp) {
    int idx = blockIdx.x * blockDim.x + threadIdx.x;
    if (idx >= Dd * Hh) return;
    int d = idx >> 9, h = idx & 511;
    int mh = (h % 127) + 1;
    float* bp = Wp + d * 1536;
    bp[h]        = W2[d * Hh + h] * ((mh <= d) ? NRL : 0.f);
    bp[512 + h]  = W2[(Dd + d) * Hh + h] * ((mh <= d) ? 1.f : 0.f);
    bp[1024 + h] = W1[h * Dd + d] * ((mh > d) ? __expf(-b2[d]) : 0.f);
}

// ---------------- weight buffer (24 VGPRs each; 3 buffers = 72) ----------
struct WBuf { v4f s0, s1, m0, m1, w0, w1; };

__device__ __forceinline__ void loadbuf(WBuf &b, const float* p) {
    b.s0 = *(const v4f*)(p);          // sigma' (masked, *NRL)
    b.s1 = *(const v4f*)(p + 4);
    b.m0 = *(const v4f*)(p + 512);    // mu (masked)
    b.m1 = *(const v4f*)(p + 516);
    b.w0 = *(const v4f*)(p + 1024);   // W1 col (masked, *E_d)
    b.w1 = *(const v4f*)(p + 1028);
    __builtin_amdgcn_sched_barrier(0);  // pin issue point
}

// ---------------- one recurrence step (pk math, lane63 reduction) --------
__device__ __forceinline__ void stepD(int u, int lane,
    v2f (&a2)[4], const WBuf &w, float xa, float xb,
    float &za, float &zb, float &ldet63)
{
    const v2f zz = {0.f, 0.f};
    v2f h0 = __builtin_elementwise_max(a2[0], zz);
    v2f h1 = __builtin_elementwise_max(a2[1], zz);
    v2f h2 = __builtin_elementwise_max(a2[2], zz);
    v2f h3 = __builtin_elementwise_max(a2[3], zz);

    v2f psA = zz, psB = zz, pmA = zz, pmB = zz;
    psA = __builtin_elementwise_fma(h0, (v2f)LOQ(w.s0), psA);
    pmA = __builtin_elementwise_fma(h0, (v2f)LOQ(w.m0), pmA);
    psB = __builtin_elementwise_fma(h1, (v2f)HIQ(w.s0), psB);
    pmB = __builtin_elementwise_fma(h1, (v2f)HIQ(w.m0), pmB);
    psA = __builtin_elementwise_fma(h2, (v2f)LOQ(w.s1), psA);
    pmA = __builtin_elementwise_fma(h2, (v2f)LOQ(w.m1), pmA);
    psB = __builtin_elementwise_fma(h3, (v2f)HIQ(w.s1), psB);
    pmB = __builtin_elementwise_fma(h3, (v2f)HIQ(w.m1), pmB);
    v2f psp = psA + psB;             // v_pk_add_f32
    v2f pmp = pmA + pmB;

    float sp = wave_sum63(psp.x + psp.y);   // valid on lane63 only
    float sm = wave_sum63(pmp.x + pmp.y);   // valid on lane63 only

    int dl = u & 63;
    float xv = bcast_lane(u < 64 ? xa : xb, dl);          // uniform
    float zd63 = (xv - sm) * __builtin_amdgcn_exp2f(sp);  // valid on lane63
    ldet63 += sp;                                          // lane63 accumulates
    float zd = bcast_lane(zd63, 63);                       // ONE broadcast
    if (dl == lane) { if (u < 64) za = zd; else zb = zd; }

    v2f zd2 = {zd, zd};
    a2[0] = __builtin_elementwise_fma(zd2, (v2f)LOQ(w.w0), a2[0]);
    a2[1] = __builtin_elementwise_fma(zd2, (v2f)HIQ(w.w0), a2[1]);
    a2[2] = __builtin_elementwise_fma(zd2, (v2f)LOQ(w.w1), a2[2]);
    a2[3] = __builtin_elementwise_fma(zd2, (v2f)HIQ(w.w1), a2[3]);
}

__global__ __launch_bounds__(64, 1) void iaf13_kernel(
    const float* __restrict__ x,
    const float* __restrict__ b1,
    const float* __restrict__ b2,
    const float* __restrict__ Wp,
    float* __restrict__ out)
{
    const int lane = (int)threadIdx.x;
    const int row  = (int)blockIdx.x;
    const int h0   = lane * 8;

    // ---- per-row state: preacts (pk pairs), bias-folded x, epilogue E ----
    v2f a2[4];
    {
        v4f t0v = *(const v4f*)(b1 + h0);
        v4f t1v = *(const v4f*)(b1 + h0 + 4);
        a2[0] = LOQ(t0v); a2[1] = HIQ(t0v);
        a2[2] = LOQ(t1v); a2[3] = HIQ(t1v);
    }
    float bsa = b2[lane],       bsb = b2[64 + lane];    // sigma biases
    float bma = b2[128 + lane], bmb = b2[192 + lane];   // mu biases
    float xa  = x[row * Dd + lane]      - bma;          // x' = x - b2_mu
    float xb  = x[row * Dd + 64 + lane] - bmb;
    float Ea  = __builtin_amdgcn_exp2f(bsa * NRL);      // E_d for za lanes
    float Eb  = __builtin_amdgcn_exp2f(bsb * NRL);      // E_d for zb lanes
    float Csum = NRL * wave_sum_bcast(bsa + bsb);       // sum_d b2[d]*NRL

    float za = 0.f, zb = 0.f, ldet = 0.f;               // ldet lives on lane63

    const float* base = Wp + h0;
    WBuf A, B, C;
    loadbuf(A, base + 0 * 1536);
    loadbuf(B, base + 1 * 1536);
    loadbuf(C, base + 2 * 1536);

#pragma unroll 1
    for (int t = 0; t < Dd - 2; t += 3) {   // t = 0,3,...,123 (42 iters)
        stepD(t + 0, lane, a2, A, xa, xb, za, zb, ldet);
        loadbuf(A, base + (size_t)(t + 3) * 1536);
        stepD(t + 1, lane, a2, B, xa, xb, za, zb, ldet);
        loadbuf(B, base + (size_t)(t + 4) * 1536);
        stepD(t + 2, lane, a2, C, xa, xb, za, zb, ldet);
        loadbuf(C, base + (size_t)((t + 5 < Dd) ? (t + 5) : 0) * 1536);
    }
    // after t=123 iter: A holds step 126, B holds step 127
    stepD(Dd - 2, lane, a2, A, xa, xb, za, zb, ldet);
    stepD(Dd - 1, lane, a2, B, xa, xb, za, zb, ldet);

    out[row * Dd + lane]      = za * Ea;       // un-fold E_d
    out[row * Dd + 64 + lane] = zb * Eb;
    float ldt = bcast_lane(ldet, 63);
    if (lane == 0) out[Bz * Dd + row] = LN2 * (ldt + Csum);
}

// ---------------- fallback (ws too small): masked direct loads ----------------
__global__ __launch_bounds__(64, 1) void iaf_fb_kernel(
    const float* __restrict__ x,  const float* __restrict__ W1,
    const float* __restrict__ b1, const float* __restrict__ W2,
    const float* __restrict__ b2, float* __restrict__ out)
{
    const int lane = (int)threadIdx.x;
    const int row  = (int)blockIdx.x;
    const int h0   = lane * 8;
    float a[8]; int mh[8];
#pragma unroll
    for (int k = 0; k < 8; ++k) { a[k] = b1[h0 + k]; mh[k] = ((h0 + k) % 127) + 1; }
    float xa  = x[row * Dd + lane], xb = x[row * Dd + 64 + lane];
    float b2a = b2[lane], b2b = b2[64 + lane], b2c = b2[128 + lane], b2d_ = b2[192 + lane];
    float za = 0.f, zb = 0.f, ld = 0.f;
    for (int d = 0; d < Dd; ++d) {
        float ps = 0.f, pm = 0.f;
#pragma unroll
        for (int k = 0; k < 8; ++k) {
            float h = fmaxf(a[k], 0.f);
            h = (mh[k] <= d) ? h : 0.f;
            ps = fmaf(h, W2[d * Hh + h0 + k], ps);
            pm = fmaf(h, W2[(Dd + d) * Hh + h0 + k], pm);
        }
        ps = wave_sum_bcast(ps);
        pm = wave_sum_bcast(pm);
        int dl = d & 63;
        float sd = ps + bcast_lane(d < 64 ? b2a : b2b, dl);
        float md = pm + bcast_lane(d < 64 ? b2c : b2d_, dl);
        float xv =      bcast_lane(d < 64 ? xa  : xb,  dl);
        float zd = (xv - md) * __expf(-sd);
        ld -= sd;
        if (dl == lane) { if (d < 64) za = zd; else zb = zd; }
#pragma unroll
        for (int k = 0; k < 8; ++k)
            if (d < mh[k]) a[k] = fmaf(zd, W1[(h0 + k) * Dd + d], a[k]);
    }
    out[row * Dd + lane]      = za;
    out[row * Dd + 64 + lane] = zb;
    if (lane == 0) out[Bz * Dd + row] = ld;
}

extern "C" void kernel_launch(void* const* d_in, const int* in_sizes, int n_in,
                              void* d_out, int out_size, void* d_ws, size_t ws_size,
                              hipStream_t stream) {
    const float* x  = (const float*)d_in[0];
    const float* W1 = (const float*)d_in[1];
    const float* b1 = (const float*)d_in[2];
    const float* W2 = (const float*)d_in[3];
    const float* b2 = (const float*)d_in[4];
    float* out = (float*)d_out;
    float* Wp  = (float*)d_ws;

    const size_t need = (size_t)Dd * 1536 * sizeof(float);  // 768 KB
    if (ws_size >= need) {
        pack_kernel<<<(Dd * Hh + 255) / 256, 256, 0, stream>>>(W1, W2, b2, Wp);
        iaf13_kernel<<<Bz, 64, 0, stream>>>(x, b1, b2, Wp, out);
    } else {
        iaf_fb_kernel<<<Bz, 64, 0, stream>>>(x, W1, b1, W2, b2, out);
    }
}